// Round 13
// baseline (333.082 us; speedup 1.0000x reference)
//
#include <hip/hip_runtime.h>

#define N_NODES 50000
#define N_EDGES 800000
#define D 64
#define NUM_LAYERS 4
#define NUM_GRAPHS 128
#define N_ALL (2 * N_NODES)
#define E_ALL (2 * N_EDGES)
#define BSHIFT 9
#define NBUCK ((N_ALL + 511) / 512)     // 196 buckets of 512 dst ids
#define CHUNK 4096                      // edges per bin_scatter block (16/thread)
#define NCHUNK ((E_ALL + CHUNK - 1) / CHUNK)  // 391

// ---------- bf16 helpers (RNE pack, shift unpack) ----------
__device__ __forceinline__ unsigned f2bf(float f) {
    unsigned u = __float_as_uint(f);
    return (u + 0x7FFFu + ((u >> 16) & 1u)) >> 16;
}
__device__ __forceinline__ float bflo(unsigned p) { return __uint_as_float(p << 16); }
__device__ __forceinline__ float bfhi(unsigned p) { return __uint_as_float(p & 0xFFFF0000u); }
__device__ __forceinline__ void acc8(float* a, uint4 v) {
    a[0] += bflo(v.x); a[1] += bfhi(v.x);
    a[2] += bflo(v.y); a[3] += bfhi(v.y);
    a[4] += bflo(v.z); a[5] += bfhi(v.z);
    a[6] += bflo(v.w); a[7] += bfhi(v.w);
}

// ---------- pass 0: coarse bucket totals + (last block) scan, fused ----------
#define BC_BLOCKS 256
__global__ __launch_bounds__(256) void bucket_count_scan(const int* __restrict__ dR,
                                                         const int* __restrict__ dX,
                                                         int* __restrict__ bucketTotal,
                                                         int* __restrict__ done,
                                                         int* __restrict__ bucketBase,
                                                         int* __restrict__ bucketCursor) {
    __shared__ int lc[NBUCK];
    __shared__ int isLast;
    int t = threadIdx.x;
    for (int j = t; j < NBUCK; j += 256) lc[j] = 0;
    __syncthreads();
    for (int e = blockIdx.x * 256 + t; e < N_EDGES; e += BC_BLOCKS * 256) {
        atomicAdd(&lc[dR[e] >> BSHIFT], 1);
        atomicAdd(&lc[(N_NODES + dX[e]) >> BSHIFT], 1);
    }
    __syncthreads();
    for (int j = t; j < NBUCK; j += 256) {
        int v = lc[j];
        if (v) atomicAdd(&bucketTotal[j], v);
    }
    __threadfence();
    if (t == 0) isLast = (atomicAdd(done, 1) == BC_BLOCKS - 1);
    __syncthreads();
    if (isLast) {
        __shared__ int s[256];
        int v = (t < NBUCK) ? bucketTotal[t] : 0;
        s[t] = v;
        __syncthreads();
        for (int off = 1; off < 256; off <<= 1) {
            int tv = (t >= off) ? s[t - off] : 0;
            __syncthreads();
            s[t] += tv;
            __syncthreads();
        }
        if (t < NBUCK) {
            int excl = s[t] - v;
            bucketBase[t] = excl;
            bucketCursor[t] = excl;
        }
        if (t == NBUCK - 1) bucketBase[NBUCK] = s[t];   // == E_ALL
    }
}

// ---------- pass 1: bin u32 pairs (d_low9<<16 | src16) by bucket; coalesced runs ----------
__global__ __launch_bounds__(256) void bin_scatter(const int* __restrict__ sR,
                                                   const int* __restrict__ dR,
                                                   const int* __restrict__ sX,
                                                   const int* __restrict__ dX,
                                                   int* __restrict__ bucketCursor,
                                                   unsigned* __restrict__ pairs) {
    __shared__ unsigned lpair[CHUNK];
    __shared__ unsigned char lbuck[CHUNK];
    __shared__ int lcnt[NBUCK];
    __shared__ int lbase[NBUCK];
    __shared__ int gbase[NBUCK];
    __shared__ int sc[256];
    __shared__ int tot;
    int t = threadIdx.x;
    for (int j = t; j < NBUCK; j += 256) lcnt[j] = 0;
    __syncthreads();

    int base = blockIdx.x * CHUNK;
    unsigned myp[16];
    int myr[16], myb[16];
#pragma unroll
    for (int i = 0; i < 16; ++i) {
        int e = base + i * 256 + t;
        if (e < E_ALL) {
            bool isR = (e < N_EDGES);
            int d = isR ? dR[e] : (N_NODES + dX[e - N_EDGES]);
            int s = isR ? sR[e] : sX[e - N_EDGES];
            myp[i] = ((unsigned)(d & 511) << 16) | (unsigned)s;
            myb[i] = d >> BSHIFT;
            myr[i] = atomicAdd(&lcnt[myb[i]], 1);
        }
    }
    __syncthreads();

    int v = (t < NBUCK) ? lcnt[t] : 0;
    sc[t] = v;
    __syncthreads();
    for (int off = 1; off < 256; off <<= 1) {
        int tv = (t >= off) ? sc[t - off] : 0;
        __syncthreads();
        sc[t] += tv;
        __syncthreads();
    }
    if (t < NBUCK) {
        lbase[t] = sc[t] - v;
        if (v > 0) gbase[t] = atomicAdd(&bucketCursor[t], v);
    }
    if (t == NBUCK - 1) tot = sc[t];
    __syncthreads();

#pragma unroll
    for (int i = 0; i < 16; ++i) {
        int e = base + i * 256 + t;
        if (e < E_ALL) {
            int p = lbase[myb[i]] + myr[i];
            lpair[p] = myp[i];
            lbuck[p] = (unsigned char)myb[i];
        }
    }
    __syncthreads();

    int total = tot;
    for (int j = t; j < total; j += 256) {
        int b = lbuck[j];
        pairs[(size_t)gbase[b] + (j - lbase[b])] = lpair[j];
    }
}

// ---------- pass 2: per bucket -- degrees+rowptr in LDS, place col; writes coalesced ----------
__global__ __launch_bounds__(256) void bucket_place(const unsigned* __restrict__ pairs,
                                                    const int* __restrict__ bucketBase,
                                                    int* __restrict__ rowptr,
                                                    unsigned short* __restrict__ col) {
    __shared__ unsigned short scol[10240];
    __shared__ int ldeg[512];
    __shared__ int lcur[512];
    __shared__ int s1[256];
    int b = blockIdx.x;
    int d0 = b << BSHIFT;
    int nd = min(512, N_ALL - d0);
    int t = threadIdx.x;
    int base = bucketBase[b];
    int cnt = bucketBase[b + 1] - base;
    ldeg[t] = 0; ldeg[t + 256] = 0;
    __syncthreads();
    for (int i = t; i < cnt; i += 256) {
        int dl = pairs[(size_t)base + i] >> 16;
        atomicAdd(&ldeg[dl], 1);
    }
    __syncthreads();
    int v0 = ldeg[2 * t], v1 = ldeg[2 * t + 1];
    int pv = v0 + v1;
    s1[t] = pv;
    __syncthreads();
    for (int off = 1; off < 256; off <<= 1) {
        int tv = (t >= off) ? s1[t - off] : 0;
        __syncthreads();
        s1[t] += tv;
        __syncthreads();
    }
    int before = s1[t] - pv;
    lcur[2 * t] = before;
    lcur[2 * t + 1] = before + v0;
    if (2 * t < nd)     rowptr[d0 + 2 * t]     = base + before;
    if (2 * t + 1 < nd) rowptr[d0 + 2 * t + 1] = base + before + v0;
    if (b == NBUCK - 1 && t == 0) rowptr[N_ALL] = base + cnt;
    __syncthreads();
    for (int i = t; i < cnt; i += 256) {
        unsigned pr = pairs[(size_t)base + i];
        int dl = pr >> 16;
        int p = atomicAdd(&lcur[dl], 1);
        scol[p] = (unsigned short)(pr & 0xFFFFu);
    }
    __syncthreads();
    for (int i = t; i < cnt; i += 256) col[base + i] = scol[i];
}

// ---------- split-edge bf16 gather, unroll 8 ----------
__global__ __launch_bounds__(256, 8) void gather_bf16(const uint4* __restrict__ xb,
                                                      uint4* __restrict__ ob,
                                                      const int* __restrict__ rowptr,
                                                      const unsigned short* __restrict__ col) {
    int t = threadIdx.x;
    int grp = t >> 4;
    int half = (t >> 3) & 1;
    int ln8 = t & 7;
    int node = blockIdx.x * 16 + grp;   // grid exactly covers 50000
    int beg = rowptr[node], end = rowptr[node + 1];
    int cnt = end - beg;
    int ch = (cnt - half + 1) >> 1;
    const unsigned short* cp = col + beg + half;
    float a[8];
    if (half == 0) {
        uint4 v = xb[(size_t)node * 8 + ln8];
        a[0] = bflo(v.x); a[1] = bfhi(v.x); a[2] = bflo(v.y); a[3] = bfhi(v.y);
        a[4] = bflo(v.z); a[5] = bfhi(v.z); a[6] = bflo(v.w); a[7] = bfhi(v.w);
    } else {
#pragma unroll
        for (int i = 0; i < 8; ++i) a[i] = 0.0f;
    }
    int i = 0;
    for (; i + 8 <= ch; i += 8) {
        int s0 = cp[2 * i],      s1 = cp[2 * i + 2],  s2 = cp[2 * i + 4],  s3 = cp[2 * i + 6];
        int s4 = cp[2 * i + 8],  s5 = cp[2 * i + 10], s6 = cp[2 * i + 12], s7 = cp[2 * i + 14];
        uint4 v0 = xb[(size_t)s0 * 8 + ln8];
        uint4 v1 = xb[(size_t)s1 * 8 + ln8];
        uint4 v2 = xb[(size_t)s2 * 8 + ln8];
        uint4 v3 = xb[(size_t)s3 * 8 + ln8];
        uint4 v4 = xb[(size_t)s4 * 8 + ln8];
        uint4 v5 = xb[(size_t)s5 * 8 + ln8];
        uint4 v6 = xb[(size_t)s6 * 8 + ln8];
        uint4 v7 = xb[(size_t)s7 * 8 + ln8];
        acc8(a, v0); acc8(a, v1); acc8(a, v2); acc8(a, v3);
        acc8(a, v4); acc8(a, v5); acc8(a, v6); acc8(a, v7);
    }
    for (; i + 4 <= ch; i += 4) {
        int s0 = cp[2 * i], s1 = cp[2 * i + 2], s2 = cp[2 * i + 4], s3 = cp[2 * i + 6];
        uint4 v0 = xb[(size_t)s0 * 8 + ln8];
        uint4 v1 = xb[(size_t)s1 * 8 + ln8];
        uint4 v2 = xb[(size_t)s2 * 8 + ln8];
        uint4 v3 = xb[(size_t)s3 * 8 + ln8];
        acc8(a, v0); acc8(a, v1); acc8(a, v2); acc8(a, v3);
    }
    for (; i < ch; ++i) acc8(a, xb[(size_t)cp[2 * i] * 8 + ln8]);
#pragma unroll
    for (int j = 0; j < 8; ++j) a[j] += __shfl_xor(a[j], 8);
    if (half == 0) {
        uint4 o;
        o.x = f2bf(a[0]) | (f2bf(a[1]) << 16);
        o.y = f2bf(a[2]) | (f2bf(a[3]) << 16);
        o.z = f2bf(a[4]) | (f2bf(a[5]) << 16);
        o.w = f2bf(a[6]) | (f2bf(a[7]) << 16);
        ob[(size_t)node * 8 + ln8] = o;
    }
}

// ---------- fused: y = relu( (x + gather(x)) @ W^T + b ) ----------
template <bool F32IN>
__global__ __launch_bounds__(256, 6) void gather_linear(const void* __restrict__ xv,
                                                        unsigned short* __restrict__ y,
                                                        const int* __restrict__ rowptr,
                                                        const unsigned short* __restrict__ col,
                                                        const float* __restrict__ W,
                                                        const float* __restrict__ b) {
    __shared__ float Wl[64 * 65];   // stride 65: Wl[o*65+k] reads conflict-free
    __shared__ float hl[16 * 64];
    int t = threadIdx.x;
#pragma unroll
    for (int i = 0; i < 16; ++i) {
        int idx = i * 256 + t;
        Wl[(idx >> 6) * 65 + (idx & 63)] = W[idx];
    }
    int grp = t >> 4;
    int node = blockIdx.x * 16 + grp;   // grid exactly covers 50000
    int beg = rowptr[node], end = rowptr[node + 1];
    if (F32IN) {
        int ln = t & 15;
        const float4* xf = (const float4*)xv;
        float4 v = xf[(size_t)node * 16 + ln];
        float a0 = v.x, a1 = v.y, a2 = v.z, a3 = v.w;
        int e = beg;
        for (; e + 4 <= end; e += 4) {
            int s0 = col[e], s1 = col[e + 1], s2 = col[e + 2], s3 = col[e + 3];
            float4 v0 = xf[(size_t)s0 * 16 + ln];
            float4 v1 = xf[(size_t)s1 * 16 + ln];
            float4 v2 = xf[(size_t)s2 * 16 + ln];
            float4 v3 = xf[(size_t)s3 * 16 + ln];
            a0 += v0.x + v1.x + v2.x + v3.x;
            a1 += v0.y + v1.y + v2.y + v3.y;
            a2 += v0.z + v1.z + v2.z + v3.z;
            a3 += v0.w + v1.w + v2.w + v3.w;
        }
        for (; e < end; ++e) {
            float4 v4 = xf[(size_t)col[e] * 16 + ln];
            a0 += v4.x; a1 += v4.y; a2 += v4.z; a3 += v4.w;
        }
        *((float4*)(hl + grp * 64 + ln * 4)) = make_float4(a0, a1, a2, a3);
    } else {
        int half = (t >> 3) & 1;
        int ln8 = t & 7;
        const uint4* xb = (const uint4*)xv;
        int cnt = end - beg;
        int ch = (cnt - half + 1) >> 1;
        const unsigned short* cp = col + beg + half;
        float a[8];
        if (half == 0) {
            uint4 v = xb[(size_t)node * 8 + ln8];
            a[0] = bflo(v.x); a[1] = bfhi(v.x); a[2] = bflo(v.y); a[3] = bfhi(v.y);
            a[4] = bflo(v.z); a[5] = bfhi(v.z); a[6] = bflo(v.w); a[7] = bfhi(v.w);
        } else {
#pragma unroll
            for (int i = 0; i < 8; ++i) a[i] = 0.0f;
        }
        int i = 0;
        for (; i + 8 <= ch; i += 8) {
            int s0 = cp[2 * i],      s1 = cp[2 * i + 2],  s2 = cp[2 * i + 4],  s3 = cp[2 * i + 6];
            int s4 = cp[2 * i + 8],  s5 = cp[2 * i + 10], s6 = cp[2 * i + 12], s7 = cp[2 * i + 14];
            uint4 v0 = xb[(size_t)s0 * 8 + ln8];
            uint4 v1 = xb[(size_t)s1 * 8 + ln8];
            uint4 v2 = xb[(size_t)s2 * 8 + ln8];
            uint4 v3 = xb[(size_t)s3 * 8 + ln8];
            uint4 v4 = xb[(size_t)s4 * 8 + ln8];
            uint4 v5 = xb[(size_t)s5 * 8 + ln8];
            uint4 v6 = xb[(size_t)s6 * 8 + ln8];
            uint4 v7 = xb[(size_t)s7 * 8 + ln8];
            acc8(a, v0); acc8(a, v1); acc8(a, v2); acc8(a, v3);
            acc8(a, v4); acc8(a, v5); acc8(a, v6); acc8(a, v7);
        }
        for (; i + 4 <= ch; i += 4) {
            int s0 = cp[2 * i], s1 = cp[2 * i + 2], s2 = cp[2 * i + 4], s3 = cp[2 * i + 6];
            uint4 v0 = xb[(size_t)s0 * 8 + ln8];
            uint4 v1 = xb[(size_t)s1 * 8 + ln8];
            uint4 v2 = xb[(size_t)s2 * 8 + ln8];
            uint4 v3 = xb[(size_t)s3 * 8 + ln8];
            acc8(a, v0); acc8(a, v1); acc8(a, v2); acc8(a, v3);
        }
        for (; i < ch; ++i) acc8(a, xb[(size_t)cp[2 * i] * 8 + ln8]);
#pragma unroll
        for (int j = 0; j < 8; ++j) a[j] += __shfl_xor(a[j], 8);
        if (half == 0) {
            float4* hp = (float4*)(hl + grp * 64 + ln8 * 8);
            hp[0] = make_float4(a[0], a[1], a[2], a[3]);
            hp[1] = make_float4(a[4], a[5], a[6], a[7]);
        }
    }
    __syncthreads();

    int o = t & 63, nb = t >> 6;
    float bo = b[o];
    float a0 = bo, a1 = bo, a2 = bo, a3 = bo;
#pragma unroll
    for (int k = 0; k < 64; ++k) {
        float w = Wl[o * 65 + k];
        a0 += hl[(nb     ) * 64 + k] * w;
        a1 += hl[(nb +  4) * 64 + k] * w;
        a2 += hl[(nb +  8) * 64 + k] * w;
        a3 += hl[(nb + 12) * 64 + k] * w;
    }
    size_t base = (size_t)blockIdx.x * 16;
    y[(base + nb     ) * 64 + o] = (unsigned short)f2bf(fmaxf(a0, 0.0f));
    y[(base + nb +  4) * 64 + o] = (unsigned short)f2bf(fmaxf(a1, 0.0f));
    y[(base + nb +  8) * 64 + o] = (unsigned short)f2bf(fmaxf(a2, 0.0f));
    y[(base + nb + 12) * 64 + o] = (unsigned short)f2bf(fmaxf(a3, 0.0f));
}

// ---------- pool: batch sorted -> contiguous segments ----------
__device__ __forceinline__ int lower_bound_dev(const int* __restrict__ a, int n, int v) {
    int lo = 0, hi = n;
    while (lo < hi) { int mid = (lo + hi) >> 1; if (a[mid] < v) lo = mid + 1; else hi = mid; }
    return lo;
}

__global__ __launch_bounds__(256) void pool_seg_bf16(const unsigned short* __restrict__ xb,
                                                     const int* __restrict__ batch,
                                                     float* __restrict__ out) {
    int g = blockIdx.x;
    int lo = lower_bound_dev(batch, N_NODES, g);
    int hi = lower_bound_dev(batch, N_NODES, g + 1);
    int lane = threadIdx.x & 63;
    int sub = threadIdx.x >> 6;
    float acc = 0.0f;
    for (int n = lo + sub; n < hi; n += 4)
        acc += __uint_as_float(((unsigned)xb[(size_t)n * 64 + lane]) << 16);
    __shared__ float red[256];
    red[threadIdx.x] = acc;
    __syncthreads();
    if (sub == 0)
        out[(size_t)g * D + lane] = red[lane] + red[64 + lane] + red[128 + lane] + red[192 + lane];
}

// ---------- host ----------
extern "C" void kernel_launch(void* const* d_in, const int* in_sizes, int n_in,
                              void* d_out, int out_size, void* d_ws, size_t ws_size,
                              hipStream_t stream) {
    const float* x_in  = (const float*)d_in[0];
    const int*   ei    = (const int*)d_in[1];
    const int*   eei   = (const int*)d_in[2];
    const int*   batch = (const int*)d_in[3];
    const float* Ws    = (const float*)d_in[4];
    const float* bs    = (const float*)d_in[5];
    float* out = (float*)d_out;

    unsigned short* A = (unsigned short*)d_ws;          // y (bf16) [N*D]
    unsigned short* B = A + (size_t)N_NODES * D;        // x' (bf16)
    unsigned short* colAll = B + (size_t)N_NODES * D;   // u16 col [E_ALL]
    unsigned* pairs = (unsigned*)(colAll + E_ALL);      // u32 pairs [E_ALL]
    int* p = (int*)(pairs + E_ALL);
    int* rowptr = p;        p += N_ALL + 1;
    int* bucketTotal = p;   p += NBUCK;
    int* done = p;          p += 1;                     // contiguous with bucketTotal (one memset)
    int* bucketBase = p;    p += NBUCK + 1;
    int* bucketCursor = p;  p += NBUCK;

    const int* e_src = ei;
    const int* e_dst = ei + N_EDGES;
    const int* x_src = eei;
    const int* x_dst = eei + N_EDGES;

    dim3 blk(256);

    // CSR build: fused count+scan -> bucketed u32-pair sort -> per-bucket rowptr+col
    hipMemsetAsync(bucketTotal, 0, (NBUCK + 1) * sizeof(int), stream);
    bucket_count_scan<<<BC_BLOCKS, blk, 0, stream>>>(e_dst, x_dst, bucketTotal, done,
                                                     bucketBase, bucketCursor);
    bin_scatter<<<NCHUNK, blk, 0, stream>>>(e_src, e_dst, x_src, x_dst, bucketCursor, pairs);
    bucket_place<<<NBUCK, blk, 0, stream>>>(pairs, bucketBase, rowptr, colAll);

    const int lgrid = N_NODES / 16;            // 3125, exact

    // layer 0: fp32 input
    gather_linear<true><<<lgrid, blk, 0, stream>>>((const void*)x_in, A,
                                                   rowptr, colAll, Ws, bs);
    gather_bf16<<<lgrid, blk, 0, stream>>>((const uint4*)A, (uint4*)B,
                                           rowptr + N_NODES, colAll);
    // layers 1..3: bf16 input
    for (int i = 1; i < NUM_LAYERS; ++i) {
        gather_linear<false><<<lgrid, blk, 0, stream>>>((const void*)B, A,
                                                        rowptr, colAll,
                                                        Ws + (size_t)i * D * D,
                                                        bs + (size_t)i * D);
        gather_bf16<<<lgrid, blk, 0, stream>>>((const uint4*)A, (uint4*)B,
                                               rowptr + N_NODES, colAll);
    }

    pool_seg_bf16<<<NUM_GRAPHS, blk, 0, stream>>>(B, batch, out);
}

// Round 14
// 325.402 us; speedup vs baseline: 1.0236x; 1.0236x over previous
//
#include <hip/hip_runtime.h>

#define N_NODES 50000
#define N_EDGES 800000
#define D 64
#define NUM_LAYERS 4
#define NUM_GRAPHS 128
#define N_ALL (2 * N_NODES)
#define E_ALL (2 * N_EDGES)
#define BSHIFT 9
#define NBUCK ((N_ALL + 511) / 512)     // 196 buckets of 512 dst ids
#define CHUNK 3072                      // edges per bin_scatter block (12/thread)
#define NCHUNK ((E_ALL + CHUNK - 1) / CHUNK)  // 521

// ---------- bf16 helpers (RNE pack, shift unpack) ----------
__device__ __forceinline__ unsigned f2bf(float f) {
    unsigned u = __float_as_uint(f);
    return (u + 0x7FFFu + ((u >> 16) & 1u)) >> 16;
}
__device__ __forceinline__ float bflo(unsigned p) { return __uint_as_float(p << 16); }
__device__ __forceinline__ float bfhi(unsigned p) { return __uint_as_float(p & 0xFFFF0000u); }
__device__ __forceinline__ void acc8(float* a, uint4 v) {
    a[0] += bflo(v.x); a[1] += bfhi(v.x);
    a[2] += bflo(v.y); a[3] += bfhi(v.y);
    a[4] += bflo(v.z); a[5] += bfhi(v.z);
    a[6] += bflo(v.w); a[7] += bfhi(v.w);
}

// ---------- pass 0: coarse bucket totals (LDS histogram, tiny global flush) ----------
#define BC_BLOCKS 256
__global__ __launch_bounds__(256) void bucket_count(const int* __restrict__ dR,
                                                    const int* __restrict__ dX,
                                                    int* __restrict__ bucketTotal) {
    __shared__ int lc[NBUCK];
    int t = threadIdx.x;
    for (int j = t; j < NBUCK; j += 256) lc[j] = 0;
    __syncthreads();
    for (int e = blockIdx.x * 256 + t; e < N_EDGES; e += BC_BLOCKS * 256) {
        atomicAdd(&lc[dR[e] >> BSHIFT], 1);
        atomicAdd(&lc[(N_NODES + dX[e]) >> BSHIFT], 1);
    }
    __syncthreads();
    for (int j = t; j < NBUCK; j += 256) {
        int v = lc[j];
        if (v) atomicAdd(&bucketTotal[j], v);
    }
}

// ---------- pass 0b: scan 196 bucket totals (single block) ----------
__global__ __launch_bounds__(256) void bucket_scan(const int* __restrict__ bucketTotal,
                                                   int* __restrict__ bucketBase,
                                                   int* __restrict__ bucketCursor) {
    __shared__ int s[256];
    int t = threadIdx.x;
    int v = (t < NBUCK) ? bucketTotal[t] : 0;
    s[t] = v;
    __syncthreads();
    for (int off = 1; off < 256; off <<= 1) {
        int tv = (t >= off) ? s[t - off] : 0;
        __syncthreads();
        s[t] += tv;
        __syncthreads();
    }
    if (t < NBUCK) {
        int excl = s[t] - v;
        bucketBase[t] = excl;
        bucketCursor[t] = excl;
    }
    if (t == NBUCK - 1) bucketBase[NBUCK] = s[t];   // == E_ALL
}

// ---------- pass 1: bin u32 pairs (d_low9<<16 | src16) by bucket; coalesced runs ----------
__global__ __launch_bounds__(256) void bin_scatter(const int* __restrict__ sR,
                                                   const int* __restrict__ dR,
                                                   const int* __restrict__ sX,
                                                   const int* __restrict__ dX,
                                                   int* __restrict__ bucketCursor,
                                                   unsigned* __restrict__ pairs) {
    __shared__ unsigned lpair[CHUNK];
    __shared__ unsigned char lbuck[CHUNK];
    __shared__ int lcnt[NBUCK];
    __shared__ int lbase[NBUCK];
    __shared__ int gbase[NBUCK];
    __shared__ int sc[256];
    __shared__ int tot;
    int t = threadIdx.x;
    for (int j = t; j < NBUCK; j += 256) lcnt[j] = 0;
    __syncthreads();

    int base = blockIdx.x * CHUNK;
    unsigned myp[12];
    int myr[12], myb[12];
#pragma unroll
    for (int i = 0; i < 12; ++i) {
        int e = base + i * 256 + t;
        if (e < E_ALL) {
            bool isR = (e < N_EDGES);
            int d = isR ? dR[e] : (N_NODES + dX[e - N_EDGES]);
            int s = isR ? sR[e] : sX[e - N_EDGES];
            myp[i] = ((unsigned)(d & 511) << 16) | (unsigned)s;
            myb[i] = d >> BSHIFT;
            myr[i] = atomicAdd(&lcnt[myb[i]], 1);
        }
    }
    __syncthreads();

    int v = (t < NBUCK) ? lcnt[t] : 0;
    sc[t] = v;
    __syncthreads();
    for (int off = 1; off < 256; off <<= 1) {
        int tv = (t >= off) ? sc[t - off] : 0;
        __syncthreads();
        sc[t] += tv;
        __syncthreads();
    }
    if (t < NBUCK) {
        lbase[t] = sc[t] - v;
        if (v > 0) gbase[t] = atomicAdd(&bucketCursor[t], v);
    }
    if (t == NBUCK - 1) tot = sc[t];
    __syncthreads();

#pragma unroll
    for (int i = 0; i < 12; ++i) {
        int e = base + i * 256 + t;
        if (e < E_ALL) {
            int p = lbase[myb[i]] + myr[i];
            lpair[p] = myp[i];
            lbuck[p] = (unsigned char)myb[i];
        }
    }
    __syncthreads();

    int total = tot;
    for (int j = t; j < total; j += 256) {
        int b = lbuck[j];
        pairs[(size_t)gbase[b] + (j - lbase[b])] = lpair[j];
    }
}

// ---------- pass 2: per bucket -- degrees+rowptr in LDS, place col; writes coalesced ----------
__global__ __launch_bounds__(256) void bucket_place(const unsigned* __restrict__ pairs,
                                                    const int* __restrict__ bucketBase,
                                                    int* __restrict__ rowptr,
                                                    unsigned short* __restrict__ col) {
    __shared__ unsigned short scol[10240];
    __shared__ int ldeg[512];
    __shared__ int lcur[512];
    __shared__ int s1[256];
    int b = blockIdx.x;
    int d0 = b << BSHIFT;
    int nd = min(512, N_ALL - d0);
    int t = threadIdx.x;
    int base = bucketBase[b];
    int cnt = bucketBase[b + 1] - base;
    ldeg[t] = 0; ldeg[t + 256] = 0;
    __syncthreads();
    for (int i = t; i < cnt; i += 256) {
        int dl = pairs[(size_t)base + i] >> 16;
        atomicAdd(&ldeg[dl], 1);
    }
    __syncthreads();
    int v0 = ldeg[2 * t], v1 = ldeg[2 * t + 1];
    int pv = v0 + v1;
    s1[t] = pv;
    __syncthreads();
    for (int off = 1; off < 256; off <<= 1) {
        int tv = (t >= off) ? s1[t - off] : 0;
        __syncthreads();
        s1[t] += tv;
        __syncthreads();
    }
    int before = s1[t] - pv;
    lcur[2 * t] = before;
    lcur[2 * t + 1] = before + v0;
    if (2 * t < nd)     rowptr[d0 + 2 * t]     = base + before;
    if (2 * t + 1 < nd) rowptr[d0 + 2 * t + 1] = base + before + v0;
    if (b == NBUCK - 1 && t == 0) rowptr[N_ALL] = base + cnt;
    __syncthreads();
    for (int i = t; i < cnt; i += 256) {
        unsigned pr = pairs[(size_t)base + i];
        int dl = pr >> 16;
        int p = atomicAdd(&lcur[dl], 1);
        scol[p] = (unsigned short)(pr & 0xFFFFu);
    }
    __syncthreads();
    for (int i = t; i < cnt; i += 256) col[base + i] = scol[i];
}

// ---------- split-edge bf16 gather, unroll 8 ----------
__global__ __launch_bounds__(256, 8) void gather_bf16(const uint4* __restrict__ xb,
                                                      uint4* __restrict__ ob,
                                                      const int* __restrict__ rowptr,
                                                      const unsigned short* __restrict__ col) {
    int t = threadIdx.x;
    int grp = t >> 4;
    int half = (t >> 3) & 1;
    int ln8 = t & 7;
    int node = blockIdx.x * 16 + grp;   // grid exactly covers 50000
    int beg = rowptr[node], end = rowptr[node + 1];
    int cnt = end - beg;
    int ch = (cnt - half + 1) >> 1;
    const unsigned short* cp = col + beg + half;
    float a[8];
    if (half == 0) {
        uint4 v = xb[(size_t)node * 8 + ln8];
        a[0] = bflo(v.x); a[1] = bfhi(v.x); a[2] = bflo(v.y); a[3] = bfhi(v.y);
        a[4] = bflo(v.z); a[5] = bfhi(v.z); a[6] = bflo(v.w); a[7] = bfhi(v.w);
    } else {
#pragma unroll
        for (int i = 0; i < 8; ++i) a[i] = 0.0f;
    }
    int i = 0;
    for (; i + 8 <= ch; i += 8) {
        int s0 = cp[2 * i],      s1 = cp[2 * i + 2],  s2 = cp[2 * i + 4],  s3 = cp[2 * i + 6];
        int s4 = cp[2 * i + 8],  s5 = cp[2 * i + 10], s6 = cp[2 * i + 12], s7 = cp[2 * i + 14];
        uint4 v0 = xb[(size_t)s0 * 8 + ln8];
        uint4 v1 = xb[(size_t)s1 * 8 + ln8];
        uint4 v2 = xb[(size_t)s2 * 8 + ln8];
        uint4 v3 = xb[(size_t)s3 * 8 + ln8];
        uint4 v4 = xb[(size_t)s4 * 8 + ln8];
        uint4 v5 = xb[(size_t)s5 * 8 + ln8];
        uint4 v6 = xb[(size_t)s6 * 8 + ln8];
        uint4 v7 = xb[(size_t)s7 * 8 + ln8];
        acc8(a, v0); acc8(a, v1); acc8(a, v2); acc8(a, v3);
        acc8(a, v4); acc8(a, v5); acc8(a, v6); acc8(a, v7);
    }
    for (; i + 4 <= ch; i += 4) {
        int s0 = cp[2 * i], s1 = cp[2 * i + 2], s2 = cp[2 * i + 4], s3 = cp[2 * i + 6];
        uint4 v0 = xb[(size_t)s0 * 8 + ln8];
        uint4 v1 = xb[(size_t)s1 * 8 + ln8];
        uint4 v2 = xb[(size_t)s2 * 8 + ln8];
        uint4 v3 = xb[(size_t)s3 * 8 + ln8];
        acc8(a, v0); acc8(a, v1); acc8(a, v2); acc8(a, v3);
    }
    for (; i < ch; ++i) acc8(a, xb[(size_t)cp[2 * i] * 8 + ln8]);
#pragma unroll
    for (int j = 0; j < 8; ++j) a[j] += __shfl_xor(a[j], 8);
    if (half == 0) {
        uint4 o;
        o.x = f2bf(a[0]) | (f2bf(a[1]) << 16);
        o.y = f2bf(a[2]) | (f2bf(a[3]) << 16);
        o.z = f2bf(a[4]) | (f2bf(a[5]) << 16);
        o.w = f2bf(a[6]) | (f2bf(a[7]) << 16);
        ob[(size_t)node * 8 + ln8] = o;
    }
}

// ---------- fused: y = relu( (x + gather(x)) @ W^T + b ) ----------
template <bool F32IN>
__global__ __launch_bounds__(256, 6) void gather_linear(const void* __restrict__ xv,
                                                        unsigned short* __restrict__ y,
                                                        const int* __restrict__ rowptr,
                                                        const unsigned short* __restrict__ col,
                                                        const float* __restrict__ W,
                                                        const float* __restrict__ b) {
    __shared__ float Wl[64 * 65];   // stride 65: Wl[o*65+k] reads conflict-free
    __shared__ float hl[16 * 64];
    int t = threadIdx.x;
#pragma unroll
    for (int i = 0; i < 16; ++i) {
        int idx = i * 256 + t;
        Wl[(idx >> 6) * 65 + (idx & 63)] = W[idx];
    }
    int grp = t >> 4;
    int node = blockIdx.x * 16 + grp;   // grid exactly covers 50000
    int beg = rowptr[node], end = rowptr[node + 1];
    if (F32IN) {
        int ln = t & 15;
        const float4* xf = (const float4*)xv;
        float4 v = xf[(size_t)node * 16 + ln];
        float a0 = v.x, a1 = v.y, a2 = v.z, a3 = v.w;
        int e = beg;
        for (; e + 4 <= end; e += 4) {
            int s0 = col[e], s1 = col[e + 1], s2 = col[e + 2], s3 = col[e + 3];
            float4 v0 = xf[(size_t)s0 * 16 + ln];
            float4 v1 = xf[(size_t)s1 * 16 + ln];
            float4 v2 = xf[(size_t)s2 * 16 + ln];
            float4 v3 = xf[(size_t)s3 * 16 + ln];
            a0 += v0.x + v1.x + v2.x + v3.x;
            a1 += v0.y + v1.y + v2.y + v3.y;
            a2 += v0.z + v1.z + v2.z + v3.z;
            a3 += v0.w + v1.w + v2.w + v3.w;
        }
        for (; e < end; ++e) {
            float4 v4 = xf[(size_t)col[e] * 16 + ln];
            a0 += v4.x; a1 += v4.y; a2 += v4.z; a3 += v4.w;
        }
        *((float4*)(hl + grp * 64 + ln * 4)) = make_float4(a0, a1, a2, a3);
    } else {
        int half = (t >> 3) & 1;
        int ln8 = t & 7;
        const uint4* xb = (const uint4*)xv;
        int cnt = end - beg;
        int ch = (cnt - half + 1) >> 1;
        const unsigned short* cp = col + beg + half;
        float a[8];
        if (half == 0) {
            uint4 v = xb[(size_t)node * 8 + ln8];
            a[0] = bflo(v.x); a[1] = bfhi(v.x); a[2] = bflo(v.y); a[3] = bfhi(v.y);
            a[4] = bflo(v.z); a[5] = bfhi(v.z); a[6] = bflo(v.w); a[7] = bfhi(v.w);
        } else {
#pragma unroll
            for (int i = 0; i < 8; ++i) a[i] = 0.0f;
        }
        int i = 0;
        for (; i + 8 <= ch; i += 8) {
            int s0 = cp[2 * i],      s1 = cp[2 * i + 2],  s2 = cp[2 * i + 4],  s3 = cp[2 * i + 6];
            int s4 = cp[2 * i + 8],  s5 = cp[2 * i + 10], s6 = cp[2 * i + 12], s7 = cp[2 * i + 14];
            uint4 v0 = xb[(size_t)s0 * 8 + ln8];
            uint4 v1 = xb[(size_t)s1 * 8 + ln8];
            uint4 v2 = xb[(size_t)s2 * 8 + ln8];
            uint4 v3 = xb[(size_t)s3 * 8 + ln8];
            uint4 v4 = xb[(size_t)s4 * 8 + ln8];
            uint4 v5 = xb[(size_t)s5 * 8 + ln8];
            uint4 v6 = xb[(size_t)s6 * 8 + ln8];
            uint4 v7 = xb[(size_t)s7 * 8 + ln8];
            acc8(a, v0); acc8(a, v1); acc8(a, v2); acc8(a, v3);
            acc8(a, v4); acc8(a, v5); acc8(a, v6); acc8(a, v7);
        }
        for (; i + 4 <= ch; i += 4) {
            int s0 = cp[2 * i], s1 = cp[2 * i + 2], s2 = cp[2 * i + 4], s3 = cp[2 * i + 6];
            uint4 v0 = xb[(size_t)s0 * 8 + ln8];
            uint4 v1 = xb[(size_t)s1 * 8 + ln8];
            uint4 v2 = xb[(size_t)s2 * 8 + ln8];
            uint4 v3 = xb[(size_t)s3 * 8 + ln8];
            acc8(a, v0); acc8(a, v1); acc8(a, v2); acc8(a, v3);
        }
        for (; i < ch; ++i) acc8(a, xb[(size_t)cp[2 * i] * 8 + ln8]);
#pragma unroll
        for (int j = 0; j < 8; ++j) a[j] += __shfl_xor(a[j], 8);
        if (half == 0) {
            float4* hp = (float4*)(hl + grp * 64 + ln8 * 8);
            hp[0] = make_float4(a[0], a[1], a[2], a[3]);
            hp[1] = make_float4(a[4], a[5], a[6], a[7]);
        }
    }
    __syncthreads();

    int o = t & 63, nb = t >> 6;
    float bo = b[o];
    float a0 = bo, a1 = bo, a2 = bo, a3 = bo;
#pragma unroll
    for (int k = 0; k < 64; ++k) {
        float w = Wl[o * 65 + k];
        a0 += hl[(nb     ) * 64 + k] * w;
        a1 += hl[(nb +  4) * 64 + k] * w;
        a2 += hl[(nb +  8) * 64 + k] * w;
        a3 += hl[(nb + 12) * 64 + k] * w;
    }
    size_t base = (size_t)blockIdx.x * 16;
    y[(base + nb     ) * 64 + o] = (unsigned short)f2bf(fmaxf(a0, 0.0f));
    y[(base + nb +  4) * 64 + o] = (unsigned short)f2bf(fmaxf(a1, 0.0f));
    y[(base + nb +  8) * 64 + o] = (unsigned short)f2bf(fmaxf(a2, 0.0f));
    y[(base + nb + 12) * 64 + o] = (unsigned short)f2bf(fmaxf(a3, 0.0f));
}

// ---------- pool: batch sorted -> contiguous segments ----------
__device__ __forceinline__ int lower_bound_dev(const int* __restrict__ a, int n, int v) {
    int lo = 0, hi = n;
    while (lo < hi) { int mid = (lo + hi) >> 1; if (a[mid] < v) lo = mid + 1; else hi = mid; }
    return lo;
}

__global__ __launch_bounds__(256) void pool_seg_bf16(const unsigned short* __restrict__ xb,
                                                     const int* __restrict__ batch,
                                                     float* __restrict__ out) {
    int g = blockIdx.x;
    int lo = lower_bound_dev(batch, N_NODES, g);
    int hi = lower_bound_dev(batch, N_NODES, g + 1);
    int lane = threadIdx.x & 63;
    int sub = threadIdx.x >> 6;
    float acc = 0.0f;
    for (int n = lo + sub; n < hi; n += 4)
        acc += __uint_as_float(((unsigned)xb[(size_t)n * 64 + lane]) << 16);
    __shared__ float red[256];
    red[threadIdx.x] = acc;
    __syncthreads();
    if (sub == 0)
        out[(size_t)g * D + lane] = red[lane] + red[64 + lane] + red[128 + lane] + red[192 + lane];
}

// ---------- host ----------
extern "C" void kernel_launch(void* const* d_in, const int* in_sizes, int n_in,
                              void* d_out, int out_size, void* d_ws, size_t ws_size,
                              hipStream_t stream) {
    const float* x_in  = (const float*)d_in[0];
    const int*   ei    = (const int*)d_in[1];
    const int*   eei   = (const int*)d_in[2];
    const int*   batch = (const int*)d_in[3];
    const float* Ws    = (const float*)d_in[4];
    const float* bs    = (const float*)d_in[5];
    float* out = (float*)d_out;

    unsigned short* A = (unsigned short*)d_ws;          // y (bf16) [N*D]
    unsigned short* B = A + (size_t)N_NODES * D;        // x' (bf16)
    unsigned short* colAll = B + (size_t)N_NODES * D;   // u16 col [E_ALL]
    unsigned* pairs = (unsigned*)(colAll + E_ALL);      // u32 pairs [E_ALL]
    int* p = (int*)(pairs + E_ALL);
    int* rowptr = p;        p += N_ALL + 1;
    int* bucketTotal = p;   p += NBUCK;
    int* bucketBase = p;    p += NBUCK + 1;
    int* bucketCursor = p;  p += NBUCK;

    const int* e_src = ei;
    const int* e_dst = ei + N_EDGES;
    const int* x_src = eei;
    const int* x_dst = eei + N_EDGES;

    dim3 blk(256);

    // CSR build: bucket totals -> scan -> bucketed u32-pair sort -> per-bucket rowptr+col
    hipMemsetAsync(bucketTotal, 0, NBUCK * sizeof(int), stream);
    bucket_count<<<BC_BLOCKS, blk, 0, stream>>>(e_dst, x_dst, bucketTotal);
    bucket_scan<<<1, blk, 0, stream>>>(bucketTotal, bucketBase, bucketCursor);
    bin_scatter<<<NCHUNK, blk, 0, stream>>>(e_src, e_dst, x_src, x_dst, bucketCursor, pairs);
    bucket_place<<<NBUCK, blk, 0, stream>>>(pairs, bucketBase, rowptr, colAll);

    const int lgrid = N_NODES / 16;            // 3125, exact

    // layer 0: fp32 input
    gather_linear<true><<<lgrid, blk, 0, stream>>>((const void*)x_in, A,
                                                   rowptr, colAll, Ws, bs);
    gather_bf16<<<lgrid, blk, 0, stream>>>((const uint4*)A, (uint4*)B,
                                           rowptr + N_NODES, colAll);
    // layers 1..3: bf16 input
    for (int i = 1; i < NUM_LAYERS; ++i) {
        gather_linear<false><<<lgrid, blk, 0, stream>>>((const void*)B, A,
                                                        rowptr, colAll,
                                                        Ws + (size_t)i * D * D,
                                                        bs + (size_t)i * D);
        gather_bf16<<<lgrid, blk, 0, stream>>>((const uint4*)A, (uint4*)B,
                                               rowptr + N_NODES, colAll);
    }

    pool_seg_bf16<<<NUM_GRAPHS, blk, 0, stream>>>(B, batch, out);
}